// Round 1
// baseline (401.283 us; speedup 1.0000x reference)
//
#include <hip/hip_runtime.h>
#include <math.h>

#define EPSF 1e-12f

static constexpr int Nn = 64, Cc = 512, Ss = 1024, Kk = 64;

// K1: invnorm[n,s] = 1/max(||x[n,:,s]||, eps)
__global__ __launch_bounds__(256) void k1_invnorm(const float* __restrict__ x,
                                                  float* __restrict__ invn) {
  int idx = blockIdx.x * 256 + threadIdx.x;  // n*S + s
  int n = idx >> 10, s = idx & 1023;
  const float* xp = x + (size_t)n * Cc * Ss + s;
  float a0 = 0.f, a1 = 0.f, a2 = 0.f, a3 = 0.f;
  for (int c = 0; c < Cc; c += 4) {
    float v0 = xp[(size_t)(c + 0) * Ss];
    float v1 = xp[(size_t)(c + 1) * Ss];
    float v2 = xp[(size_t)(c + 2) * Ss];
    float v3 = xp[(size_t)(c + 3) * Ss];
    a0 = fmaf(v0, v0, a0); a1 = fmaf(v1, v1, a1);
    a2 = fmaf(v2, v2, a2); a3 = fmaf(v3, v3, a3);
  }
  float acc = (a0 + a1) + (a2 + a3);
  invn[idx] = 1.0f / fmaxf(sqrtf(acc), EPSF);
}

// K2: logits[n,k,s] = sum_c w[k,c]*xn[n,c,s]; softmax over k; write a, atomic suma.
// block: one n, 64-s tile, all 64 k. thread t: k in {q,q+16,q+32,q+48} (q=t>>4),
// s in {m,m+16,m+32,m+48} (m=t&15). 4x4 register tile, 64x64 LDS tiles.
__global__ __launch_bounds__(256) void k2_logits_softmax(
    const float* __restrict__ x, const float* __restrict__ w,
    const float* __restrict__ invn, float* __restrict__ a,
    float* __restrict__ suma) {
  __shared__ __align__(16) float xs[64][68];  // [s_local][c_local] (transposed)
  __shared__ __align__(16) float wl[64][68];  // [k][c_local]; reused as lg[k][s]
  __shared__ float pred[4][64];
  __shared__ float smax[64];
  __shared__ float srinv[64];
  __shared__ float invs[64];

  const int n = blockIdx.y;
  const int s0 = blockIdx.x * 64;
  const int t = threadIdx.x;
  const int m = t & 15;
  const int q = t >> 4;

  if (t < 64) invs[t] = invn[(n << 10) + s0 + t];
  __syncthreads();

  float acc[4][4];
#pragma unroll
  for (int i = 0; i < 4; ++i)
#pragma unroll
    for (int j = 0; j < 4; ++j) acc[i][j] = 0.f;

  for (int c0 = 0; c0 < Cc; c0 += 64) {
#pragma unroll
    for (int i = 0; i < 16; ++i) {
      int id = t + i * 256;
      int hi = id >> 6, lo = id & 63;
      // x tile transposed into [s][c]; coalesced global read along s
      xs[lo][hi] = x[((size_t)(n * Cc + c0 + hi) << 10) + s0 + lo] * invs[lo];
      // w tile [k][c]; coalesced along c
      wl[hi][lo] = w[(hi << 9) + c0 + lo];
    }
    __syncthreads();
#pragma unroll 4
    for (int cc = 0; cc < 64; cc += 4) {
      float4 wv[4], xv[4];
#pragma unroll
      for (int i = 0; i < 4; ++i) wv[i] = *(const float4*)&wl[q + 16 * i][cc];
#pragma unroll
      for (int j = 0; j < 4; ++j) xv[j] = *(const float4*)&xs[m + 16 * j][cc];
#pragma unroll
      for (int i = 0; i < 4; ++i)
#pragma unroll
        for (int j = 0; j < 4; ++j) {
          acc[i][j] = fmaf(wv[i].x, xv[j].x, acc[i][j]);
          acc[i][j] = fmaf(wv[i].y, xv[j].y, acc[i][j]);
          acc[i][j] = fmaf(wv[i].z, xv[j].z, acc[i][j]);
          acc[i][j] = fmaf(wv[i].w, xv[j].w, acc[i][j]);
        }
    }
    __syncthreads();
  }

  // dump logits into wl (now lg[k][s])
#pragma unroll
  for (int i = 0; i < 4; ++i)
#pragma unroll
    for (int j = 0; j < 4; ++j) wl[q + 16 * i][m + 16 * j] = acc[i][j];
  __syncthreads();

  // softmax over k for each s; thread t: s = t&63, k-quarter = t>>6 (== wave id)
  const int s = t & 63;
  const int kq = t >> 6;
  float mx = -3.0e38f;
#pragma unroll
  for (int i = 0; i < 16; ++i) mx = fmaxf(mx, wl[kq * 16 + i][s]);
  pred[kq][s] = mx;
  __syncthreads();
  if (t < 64)
    smax[t] = fmaxf(fmaxf(pred[0][t], pred[1][t]), fmaxf(pred[2][t], pred[3][t]));
  __syncthreads();
  const float mxs = smax[s];
  float ps = 0.f;
#pragma unroll
  for (int i = 0; i < 16; ++i) {
    float e = __expf(wl[kq * 16 + i][s] - mxs);
    wl[kq * 16 + i][s] = e;
    ps += e;
  }
  pred[kq][s] = ps;
  __syncthreads();
  if (t < 64)
    srinv[t] = 1.0f / (pred[0][t] + pred[1][t] + pred[2][t] + pred[3][t]);
  __syncthreads();
  const float rinv = srinv[s];
#pragma unroll
  for (int i = 0; i < 16; ++i) {
    int k = kq * 16 + i;
    float v = wl[k][s] * rinv;
    a[((size_t)((n << 6) + k) << 10) + s0 + s] = v;
    float r = v;
#pragma unroll
    for (int off = 32; off > 0; off >>= 1) r += __shfl_xor(r, off, 64);
    if (s == 0) atomicAdd(&suma[(n << 6) + k], r);
  }
}

// K3: vlad[n,k,c] = sum_s a[n,k,s]*xn[n,c,s] - suma[n,k]*cent[k,c]; atomic rnorm2.
// block: one n, 64-c tile, all 64 k. thread: k = q+16i, c = m+16j.
__global__ __launch_bounds__(256) void k3_vlad(
    const float* __restrict__ x, const float* __restrict__ a,
    const float* __restrict__ invn, const float* __restrict__ cent,
    const float* __restrict__ suma, float* __restrict__ vlad,
    float* __restrict__ rnorm2) {
  __shared__ __align__(16) float at[64][68];  // [k][s_local]
  __shared__ __align__(16) float xt[64][68];  // [c_local][s_local]
  __shared__ float invs[1024];
  const int n = blockIdx.y;
  const int c0 = blockIdx.x * 64;
  const int t = threadIdx.x;
  const int m = t & 15;
  const int q = t >> 4;

#pragma unroll
  for (int i = 0; i < 4; ++i) invs[t + i * 256] = invn[(n << 10) + t + i * 256];
  __syncthreads();

  float acc[4][4];
#pragma unroll
  for (int i = 0; i < 4; ++i)
#pragma unroll
    for (int j = 0; j < 4; ++j) acc[i][j] = 0.f;

  for (int s0 = 0; s0 < Ss; s0 += 64) {
#pragma unroll
    for (int i = 0; i < 16; ++i) {
      int id = t + i * 256;
      int rl = id >> 6, sl = id & 63;
      at[rl][sl] = a[((size_t)((n << 6) + rl) << 10) + s0 + sl];
      xt[rl][sl] = x[((size_t)(n * Cc + c0 + rl) << 10) + s0 + sl] * invs[s0 + sl];
    }
    __syncthreads();
#pragma unroll 2
    for (int ss = 0; ss < 64; ss += 4) {
      float4 av[4], xv[4];
#pragma unroll
      for (int i = 0; i < 4; ++i) av[i] = *(const float4*)&at[q + 16 * i][ss];
#pragma unroll
      for (int j = 0; j < 4; ++j) xv[j] = *(const float4*)&xt[m + 16 * j][ss];
#pragma unroll
      for (int i = 0; i < 4; ++i)
#pragma unroll
        for (int j = 0; j < 4; ++j) {
          acc[i][j] = fmaf(av[i].x, xv[j].x, acc[i][j]);
          acc[i][j] = fmaf(av[i].y, xv[j].y, acc[i][j]);
          acc[i][j] = fmaf(av[i].z, xv[j].z, acc[i][j]);
          acc[i][j] = fmaf(av[i].w, xv[j].w, acc[i][j]);
        }
    }
    __syncthreads();
  }

#pragma unroll
  for (int i = 0; i < 4; ++i) {
    int k = q + 16 * i;
    float sa = suma[(n << 6) + k];
    float r2 = 0.f;
#pragma unroll
    for (int j = 0; j < 4; ++j) {
      int c = m + 16 * j;
      float val = acc[i][j] - sa * cent[(k << 9) + c0 + c];
      vlad[((size_t)((n << 6) + k) << 9) + c0 + c] = val;
      r2 = fmaf(val, val, r2);
    }
#pragma unroll
    for (int off = 8; off > 0; off >>= 1) r2 += __shfl_xor(r2, off, 64);
    if (m == 0) atomicAdd(&rnorm2[(n << 6) + k], r2);
  }
}

// K4: fac[n,k] = (1/max(rn,eps)) * (1/max(sqrt(sum_k (rn*f)^2), eps))
__global__ __launch_bounds__(64) void k4_factors(const float* __restrict__ rnorm2,
                                                 float* __restrict__ fac) {
  int n = blockIdx.x, k = threadIdx.x;
  float r2 = rnorm2[(n << 6) + k];
  float rn = sqrtf(r2);
  float f = 1.0f / fmaxf(rn, EPSF);
  float nr = rn * f;
  float g = nr * nr;
#pragma unroll
  for (int off = 32; off > 0; off >>= 1) g += __shfl_xor(g, off, 64);
  fac[(n << 6) + k] = f * (1.0f / fmaxf(sqrtf(g), EPSF));
}

// K5: out *= fac  (in place; d_out fully rewritten by K3 each call)
__global__ __launch_bounds__(256) void k5_scale(const float* __restrict__ vlad,
                                                const float* __restrict__ fac,
                                                float* __restrict__ out) {
  int idx = blockIdx.x * 256 + threadIdx.x;  // float4 index
  float4 v = ((const float4*)vlad)[idx];
  float f = fac[idx >> 7];  // idx*4/512
  float4 o;
  o.x = v.x * f; o.y = v.y * f; o.z = v.z * f; o.w = v.w * f;
  ((float4*)out)[idx] = o;
}

extern "C" void kernel_launch(void* const* d_in, const int* in_sizes, int n_in,
                              void* d_out, int out_size, void* d_ws, size_t ws_size,
                              hipStream_t stream) {
  (void)in_sizes; (void)n_in; (void)out_size; (void)ws_size;
  const float* x = (const float*)d_in[0];     // (64,512,32,32)
  const float* w = (const float*)d_in[1];     // (64,512)
  const float* cent = (const float*)d_in[2];  // (64,512)
  float* out = (float*)d_out;                 // (64, 64*512)

  float* ws = (float*)d_ws;
  float* invn = ws;               // 65536
  float* suma = invn + 65536;     // 4096
  float* rnorm2 = suma + 4096;    // 4096 (contiguous with suma for one memset)
  float* fac = rnorm2 + 4096;     // 4096
  float* a = fac + 4096;          // 4194304  (~16.4 MB ws total)

  hipMemsetAsync(suma, 0, 2 * 4096 * sizeof(float), stream);
  k1_invnorm<<<256, 256, 0, stream>>>(x, invn);
  k2_logits_softmax<<<dim3(16, 64), 256, 0, stream>>>(x, w, invn, a, suma);
  k3_vlad<<<dim3(8, 64), 256, 0, stream>>>(x, a, invn, cent, suma, out, rnorm2);
  k4_factors<<<64, 64, 0, stream>>>(rnorm2, fac);
  k5_scale<<<2048, 256, 0, stream>>>(out, fac, out);
}

// Round 2
// 261.938 us; speedup vs baseline: 1.5320x; 1.5320x over previous
//
#include <hip/hip_runtime.h>
#include <hip/hip_bf16.h>
#include <math.h>

#define EPSF 1e-12f

typedef __attribute__((ext_vector_type(8))) short bf16x8;
typedef __attribute__((ext_vector_type(4))) float f32x4;
typedef __attribute__((ext_vector_type(4))) short short4v;
typedef __attribute__((ext_vector_type(4))) unsigned short ushort4v;

static __device__ __forceinline__ short f2bf(float f) {
  union { __hip_bfloat16 h; short s; } u;
  u.h = __float2bfloat16(f);
  return u.s;
}

// K2: logits = (w @ x) * invn[s]  via bf16 MFMA; fused per-s L2-norm (k1);
// softmax over k; writes a' = a*invn (bf16) and suma (fp32 atomics).
// Block: one (n, 64-s tile). 4 waves, wave w owns k-rows [16w,16w+16).
__global__ __launch_bounds__(256) void k2_mfma(
    const float* __restrict__ x, const float* __restrict__ w,
    unsigned short* __restrict__ ap, float* __restrict__ suma) {
  __shared__ __align__(16) float xf[64][68];   // [c_local][s_local] fp32
  __shared__ __align__(16) short wb[64][72];   // [k][c_local] bf16
  __shared__ __align__(16) float red[4][64];   // per-wave reduction scratch
  __shared__ float invs[64];
  __shared__ float gmaxs[64];
  __shared__ float gsums[64];

  const int n = blockIdx.y;
  const int s0 = blockIdx.x << 6;
  const int t = threadIdx.x;
  const int lane = t & 63;
  const int wid = t >> 6;        // wave id = k-band
  const int col = t & 15;        // MFMA col (s) / frag row
  const int quad = (t >> 4) & 3; // MFMA quad
  const int cr = t >> 4;         // staging row 0..15
  const int sg = t & 15;         // staging float4 col

  f32x4 acc[4] = {{0,0,0,0},{0,0,0,0},{0,0,0,0},{0,0,0,0}};
  float ssq0 = 0.f, ssq1 = 0.f, ssq2 = 0.f, ssq3 = 0.f;

  for (int c0 = 0; c0 < 512; c0 += 64) {
#pragma unroll
    for (int p = 0; p < 4; ++p) {
      int c = cr + (p << 4);
      float4 g = *(const float4*)&x[((size_t)((n << 9) + c0 + c) << 10) + s0 + (sg << 2)];
      *(float4*)&xf[c][sg << 2] = g;
      ssq0 = fmaf(g.x, g.x, ssq0); ssq1 = fmaf(g.y, g.y, ssq1);
      ssq2 = fmaf(g.z, g.z, ssq2); ssq3 = fmaf(g.w, g.w, ssq3);
      float4 gw = *(const float4*)&w[(c << 9) + c0 + (sg << 2)];  // w[k=c][c0+4sg]
      short4v hw; hw.x = f2bf(gw.x); hw.y = f2bf(gw.y); hw.z = f2bf(gw.z); hw.w = f2bf(gw.w);
      *(short4v*)&wb[c][sg << 2] = hw;
    }
    __syncthreads();
#pragma unroll
    for (int cc = 0; cc < 64; cc += 32) {
      bf16x8 af = *(const bf16x8*)&wb[(wid << 4) + col][cc + (quad << 3)];
      int cb = cc + (quad << 3);
#pragma unroll
      for (int sgr = 0; sgr < 4; ++sgr) {
        int sc = (sgr << 4) + col;
        bf16x8 bfr;
#pragma unroll
        for (int j = 0; j < 8; ++j) bfr[j] = f2bf(xf[cb + j][sc]);  // strided gather (4-way)
        acc[sgr] = __builtin_amdgcn_mfma_f32_16x16x32_bf16(af, bfr, acc[sgr], 0, 0, 0);
      }
    }
    __syncthreads();
  }

  // ---- per-s inverse norm (thread's 4 s fixed = 4sg..4sg+3) ----
  ssq0 += __shfl_xor(ssq0, 16, 64); ssq0 += __shfl_xor(ssq0, 32, 64);
  ssq1 += __shfl_xor(ssq1, 16, 64); ssq1 += __shfl_xor(ssq1, 32, 64);
  ssq2 += __shfl_xor(ssq2, 16, 64); ssq2 += __shfl_xor(ssq2, 32, 64);
  ssq3 += __shfl_xor(ssq3, 16, 64); ssq3 += __shfl_xor(ssq3, 32, 64);
  if (lane < 16) {
    float4 v; v.x = ssq0; v.y = ssq1; v.z = ssq2; v.w = ssq3;
    *(float4*)&red[wid][sg << 2] = v;
  }
  __syncthreads();
  if (t < 64) {
    float tot = red[0][t] + red[1][t] + red[2][t] + red[3][t];
    invs[t] = 1.0f / fmaxf(sqrtf(tot), EPSF);
  }
  __syncthreads();

  // ---- softmax over k for each s ----
  float li[4];
#pragma unroll
  for (int sgr = 0; sgr < 4; ++sgr) li[sgr] = invs[(sgr << 4) + col];
  float le[4][4];
#pragma unroll
  for (int sgr = 0; sgr < 4; ++sgr)
#pragma unroll
    for (int r = 0; r < 4; ++r) le[sgr][r] = acc[sgr][r] * li[sgr];

  float mx[4];
#pragma unroll
  for (int sgr = 0; sgr < 4; ++sgr) {
    float m = fmaxf(fmaxf(le[sgr][0], le[sgr][1]), fmaxf(le[sgr][2], le[sgr][3]));
    m = fmaxf(m, __shfl_xor(m, 16, 64));
    m = fmaxf(m, __shfl_xor(m, 32, 64));
    mx[sgr] = m;
  }
  if (lane < 16) {
#pragma unroll
    for (int sgr = 0; sgr < 4; ++sgr) red[wid][(sgr << 4) + sg] = mx[sgr];
  }
  __syncthreads();
  if (t < 64)
    gmaxs[t] = fmaxf(fmaxf(red[0][t], red[1][t]), fmaxf(red[2][t], red[3][t]));
  __syncthreads();

  float ps[4];
#pragma unroll
  for (int sgr = 0; sgr < 4; ++sgr) {
    float gm = gmaxs[(sgr << 4) + col];
    float p = 0.f;
#pragma unroll
    for (int r = 0; r < 4; ++r) {
      float e = __expf(le[sgr][r] - gm);
      le[sgr][r] = e;
      p += e;
    }
    p += __shfl_xor(p, 16, 64);
    p += __shfl_xor(p, 32, 64);
    ps[sgr] = p;
  }
  if (lane < 16) {
#pragma unroll
    for (int sgr = 0; sgr < 4; ++sgr) red[wid][(sgr << 4) + sg] = ps[sgr];
  }
  __syncthreads();
  if (t < 64) gsums[t] = red[0][t] + red[1][t] + red[2][t] + red[3][t];
  __syncthreads();

  // ---- a, a' = a*invn, suma ----
  float sk[4] = {0.f, 0.f, 0.f, 0.f};
#pragma unroll
  for (int sgr = 0; sgr < 4; ++sgr) {
    float rinv = 1.0f / gsums[(sgr << 4) + col];
#pragma unroll
    for (int r = 0; r < 4; ++r) {
      float av = le[sgr][r] * rinv;            // a
      sk[r] += av;
      float apv = av * li[sgr];                // a' = a*invn[s]
      int k = (wid << 4) + (quad << 2) + r;
      ap[((size_t)((n << 6) + k) << 10) + s0 + (sgr << 4) + col] =
          (unsigned short)f2bf(apv);
    }
  }
#pragma unroll
  for (int r = 0; r < 4; ++r) {
    sk[r] += __shfl_xor(sk[r], 1, 64);
    sk[r] += __shfl_xor(sk[r], 2, 64);
    sk[r] += __shfl_xor(sk[r], 4, 64);
    sk[r] += __shfl_xor(sk[r], 8, 64);
  }
  if (col == 0) {
#pragma unroll
    for (int r = 0; r < 4; ++r)
      atomicAdd(&suma[(n << 6) + (wid << 4) + (quad << 2) + r], sk[r]);
  }
}

// K3: vlad^T[c,k] = sum_s x[c,s]*a'[k,s]  (bf16 MFMA, x as A, a' as B),
// then - suma[k]*cent[k,c], rnorm2 atomics, LDS-transposed coalesced store.
__global__ __launch_bounds__(256) void k3_mfma(
    const float* __restrict__ x, const unsigned short* __restrict__ ap,
    const float* __restrict__ cent, const float* __restrict__ suma,
    float* __restrict__ out, float* __restrict__ rnorm2) {
  __shared__ __align__(16) float xf[64][68];   // [c_local][s_local]; reused as lt[k][c]
  __shared__ __align__(16) short at[64][72];   // [k][s_local] bf16

  const int n = blockIdx.y;
  const int c0 = blockIdx.x << 6;
  const int t = threadIdx.x;
  const int lane = t & 63;
  const int wid = t >> 6;        // c-band
  const int col = t & 15;
  const int quad = (t >> 4) & 3;
  const int cr = t >> 4;
  const int sg = t & 15;

  f32x4 acc[4] = {{0,0,0,0},{0,0,0,0},{0,0,0,0},{0,0,0,0}};

  for (int s0 = 0; s0 < 1024; s0 += 64) {
#pragma unroll
    for (int p = 0; p < 4; ++p) {
      int c = cr + (p << 4);
      float4 g = *(const float4*)&x[((size_t)((n << 9) + c0 + c) << 10) + s0 + (sg << 2)];
      *(float4*)&xf[c][sg << 2] = g;
      ushort4v a4 = *(const ushort4v*)&ap[((size_t)((n << 6) + c) << 10) + s0 + (sg << 2)];
      *(ushort4v*)&at[c][sg << 2] = a4;
    }
    __syncthreads();
#pragma unroll
    for (int ss = 0; ss < 64; ss += 32) {
      float4 a0 = *(const float4*)&xf[(wid << 4) + col][ss + (quad << 3)];
      float4 a1 = *(const float4*)&xf[(wid << 4) + col][ss + (quad << 3) + 4];
      bf16x8 af;
      af[0] = f2bf(a0.x); af[1] = f2bf(a0.y); af[2] = f2bf(a0.z); af[3] = f2bf(a0.w);
      af[4] = f2bf(a1.x); af[5] = f2bf(a1.y); af[6] = f2bf(a1.z); af[7] = f2bf(a1.w);
#pragma unroll
      for (int kt = 0; kt < 4; ++kt) {
        bf16x8 bfr = *(const bf16x8*)&at[(kt << 4) + col][ss + (quad << 3)];
        acc[kt] = __builtin_amdgcn_mfma_f32_16x16x32_bf16(af, bfr, acc[kt], 0, 0, 0);
      }
    }
    __syncthreads();
  }

  // epilogue: lane holds D[c = wid*16+quad*4+r][k = kt*16+col]
  float sa[4];
#pragma unroll
  for (int kt = 0; kt < 4; ++kt) sa[kt] = suma[(n << 6) + (kt << 4) + col];
  const int crow = (wid << 4) + (quad << 2);
  float r2[4] = {0.f, 0.f, 0.f, 0.f};
#pragma unroll
  for (int kt = 0; kt < 4; ++kt) {
    int k = (kt << 4) + col;
#pragma unroll
    for (int r = 0; r < 4; ++r) {
      int c = crow + r;
      float ce = cent[(k << 9) + c0 + c];
      float val = acc[kt][r] - sa[kt] * ce;
      r2[kt] = fmaf(val, val, r2[kt]);
      xf[k][c] = val;  // lt[k][c_local]
    }
  }
#pragma unroll
  for (int kt = 0; kt < 4; ++kt) {
    r2[kt] += __shfl_xor(r2[kt], 16, 64);
    r2[kt] += __shfl_xor(r2[kt], 32, 64);
  }
  if (lane < 16) {
#pragma unroll
    for (int kt = 0; kt < 4; ++kt)
      atomicAdd(&rnorm2[(n << 6) + (kt << 4) + sg], r2[kt]);
  }
  __syncthreads();
  // coalesced store of the 64k x 64c tile
#pragma unroll
  for (int u = 0; u < 4; ++u) {
    int k = t >> 2;
    int c = ((t & 3) << 2) + (u << 4);
    float4 v = *(const float4*)&xf[k][c];
    *(float4*)&out[((size_t)((n << 6) + k) << 9) + c0 + c] = v;
  }
}

// K4: fac[n,k] = intra-norm factor * global-norm factor
__global__ __launch_bounds__(64) void k4_factors(const float* __restrict__ rnorm2,
                                                 float* __restrict__ fac) {
  int n = blockIdx.x, k = threadIdx.x;
  float r2 = rnorm2[(n << 6) + k];
  float rn = sqrtf(r2);
  float f = 1.0f / fmaxf(rn, EPSF);
  float nr = rn * f;
  float g = nr * nr;
#pragma unroll
  for (int off = 32; off > 0; off >>= 1) g += __shfl_xor(g, off, 64);
  fac[(n << 6) + k] = f * (1.0f / fmaxf(sqrtf(g), EPSF));
}

// K5: out *= fac  (in place; d_out fully rewritten by K3 each call)
__global__ __launch_bounds__(256) void k5_scale(const float* __restrict__ vlad,
                                                const float* __restrict__ fac,
                                                float* __restrict__ out) {
  int idx = blockIdx.x * 256 + threadIdx.x;  // float4 index
  float4 v = ((const float4*)vlad)[idx];
  float f = fac[idx >> 7];
  float4 o;
  o.x = v.x * f; o.y = v.y * f; o.z = v.z * f; o.w = v.w * f;
  ((float4*)out)[idx] = o;
}

extern "C" void kernel_launch(void* const* d_in, const int* in_sizes, int n_in,
                              void* d_out, int out_size, void* d_ws, size_t ws_size,
                              hipStream_t stream) {
  (void)in_sizes; (void)n_in; (void)out_size; (void)ws_size;
  const float* x = (const float*)d_in[0];     // (64,512,32,32)
  const float* w = (const float*)d_in[1];     // (64,512)
  const float* cent = (const float*)d_in[2];  // (64,512)
  float* out = (float*)d_out;                 // (64, 64*512)

  float* ws = (float*)d_ws;
  float* suma = ws;                                   // 4096
  float* rnorm2 = ws + 4096;                          // 4096
  float* fac = ws + 8192;                             // 4096
  unsigned short* ap = (unsigned short*)(ws + 12288); // 64*64*1024 bf16 = 8 MB

  hipMemsetAsync(ws, 0, 8192 * sizeof(float), stream);  // suma + rnorm2
  k2_mfma<<<dim3(16, 64), 256, 0, stream>>>(x, w, ap, suma);
  k3_mfma<<<dim3(8, 64), 256, 0, stream>>>(x, ap, cent, suma, out, rnorm2);
  k4_factors<<<64, 64, 0, stream>>>(rnorm2, fac);
  k5_scale<<<2048, 256, 0, stream>>>(out, fac, out);
}

// Round 3
// 258.433 us; speedup vs baseline: 1.5528x; 1.0136x over previous
//
#include <hip/hip_runtime.h>
#include <hip/hip_bf16.h>
#include <math.h>

#define EPSF 1e-12f

typedef __attribute__((ext_vector_type(8))) short bf16x8;
typedef __attribute__((ext_vector_type(4))) float f32x4;
typedef __attribute__((ext_vector_type(4))) short short4v;
typedef __attribute__((ext_vector_type(4))) unsigned short ushort4v;

static __device__ __forceinline__ short f2bf(float f) {
  union { __hip_bfloat16 h; short s; } u;
  u.h = __float2bfloat16(f);
  return u.s;
}

// K2: logits = (w @ x) * invn[s]  via bf16 MFMA; fused per-s L2-norm;
// softmax over k; writes a' = a*invn (bf16) and suma (fp32 atomics).
// Block: one (n, 64-s tile). 4 waves, wave w owns k-rows [16w,16w+16).
// xf pitch 70: gather bank = (70*(cb+j)+col)%32; 8*quad*70 % 32 = 16*quad
// -> 2-way aliasing only (free per m136). Pitch 68 was 4-way (1.58x).
__global__ __launch_bounds__(256) void k2_mfma(
    const float* __restrict__ x, const float* __restrict__ w,
    unsigned short* __restrict__ ap, float* __restrict__ suma) {
  __shared__ __align__(16) float xf[64][70];   // [c_local][s_local] fp32
  __shared__ __align__(16) short wb[64][72];   // [k][c_local] bf16
  __shared__ __align__(16) float red[4][64];   // per-wave reduction scratch
  __shared__ float invs[64];
  __shared__ float gmaxs[64];
  __shared__ float gsums[64];

  const int n = blockIdx.y;
  const int s0 = blockIdx.x << 6;
  const int t = threadIdx.x;
  const int lane = t & 63;
  const int wid = t >> 6;        // wave id = k-band
  const int col = t & 15;        // MFMA col (s) / frag row
  const int quad = (t >> 4) & 3; // MFMA quad
  const int cr = t >> 4;         // staging row 0..15
  const int sg = t & 15;         // staging float4 col

  f32x4 acc[4] = {{0,0,0,0},{0,0,0,0},{0,0,0,0},{0,0,0,0}};
  float ssq0 = 0.f, ssq1 = 0.f, ssq2 = 0.f, ssq3 = 0.f;

  for (int c0 = 0; c0 < 512; c0 += 64) {
#pragma unroll
    for (int p = 0; p < 4; ++p) {
      int c = cr + (p << 4);
      float4 g = *(const float4*)&x[((size_t)((n << 9) + c0 + c) << 10) + s0 + (sg << 2)];
      float2 glo; glo.x = g.x; glo.y = g.y;
      float2 ghi; ghi.x = g.z; ghi.y = g.w;
      *(float2*)&xf[c][sg << 2] = glo;
      *(float2*)&xf[c][(sg << 2) + 2] = ghi;
      ssq0 = fmaf(g.x, g.x, ssq0); ssq1 = fmaf(g.y, g.y, ssq1);
      ssq2 = fmaf(g.z, g.z, ssq2); ssq3 = fmaf(g.w, g.w, ssq3);
      float4 gw = *(const float4*)&w[(c << 9) + c0 + (sg << 2)];  // w[k=c][c0+4sg]
      short4v hw; hw.x = f2bf(gw.x); hw.y = f2bf(gw.y); hw.z = f2bf(gw.z); hw.w = f2bf(gw.w);
      *(short4v*)&wb[c][sg << 2] = hw;
    }
    __syncthreads();
#pragma unroll
    for (int cc = 0; cc < 64; cc += 32) {
      bf16x8 af = *(const bf16x8*)&wb[(wid << 4) + col][cc + (quad << 3)];
      int cb = cc + (quad << 3);
#pragma unroll
      for (int sgr = 0; sgr < 4; ++sgr) {
        int sc = (sgr << 4) + col;
        bf16x8 bfr;
#pragma unroll
        for (int j = 0; j < 8; ++j) bfr[j] = f2bf(xf[cb + j][sc]);  // 2-way (free)
        acc[sgr] = __builtin_amdgcn_mfma_f32_16x16x32_bf16(af, bfr, acc[sgr], 0, 0, 0);
      }
    }
    __syncthreads();
  }

  // ---- per-s inverse norm (thread's 4 s fixed = 4sg..4sg+3) ----
  ssq0 += __shfl_xor(ssq0, 16, 64); ssq0 += __shfl_xor(ssq0, 32, 64);
  ssq1 += __shfl_xor(ssq1, 16, 64); ssq1 += __shfl_xor(ssq1, 32, 64);
  ssq2 += __shfl_xor(ssq2, 16, 64); ssq2 += __shfl_xor(ssq2, 32, 64);
  ssq3 += __shfl_xor(ssq3, 16, 64); ssq3 += __shfl_xor(ssq3, 32, 64);
  if (lane < 16) {
    float4 v; v.x = ssq0; v.y = ssq1; v.z = ssq2; v.w = ssq3;
    *(float4*)&red[wid][sg << 2] = v;
  }
  __syncthreads();
  if (t < 64) {
    float tot = red[0][t] + red[1][t] + red[2][t] + red[3][t];
    invs[t] = 1.0f / fmaxf(sqrtf(tot), EPSF);
  }
  __syncthreads();

  // ---- softmax over k for each s ----
  float li[4];
#pragma unroll
  for (int sgr = 0; sgr < 4; ++sgr) li[sgr] = invs[(sgr << 4) + col];
  float le[4][4];
#pragma unroll
  for (int sgr = 0; sgr < 4; ++sgr)
#pragma unroll
    for (int r = 0; r < 4; ++r) le[sgr][r] = acc[sgr][r] * li[sgr];

  float mx[4];
#pragma unroll
  for (int sgr = 0; sgr < 4; ++sgr) {
    float m = fmaxf(fmaxf(le[sgr][0], le[sgr][1]), fmaxf(le[sgr][2], le[sgr][3]));
    m = fmaxf(m, __shfl_xor(m, 16, 64));
    m = fmaxf(m, __shfl_xor(m, 32, 64));
    mx[sgr] = m;
  }
  if (lane < 16) {
#pragma unroll
    for (int sgr = 0; sgr < 4; ++sgr) red[wid][(sgr << 4) + sg] = mx[sgr];
  }
  __syncthreads();
  if (t < 64)
    gmaxs[t] = fmaxf(fmaxf(red[0][t], red[1][t]), fmaxf(red[2][t], red[3][t]));
  __syncthreads();

  float ps[4];
#pragma unroll
  for (int sgr = 0; sgr < 4; ++sgr) {
    float gm = gmaxs[(sgr << 4) + col];
    float p = 0.f;
#pragma unroll
    for (int r = 0; r < 4; ++r) {
      float e = __expf(le[sgr][r] - gm);
      le[sgr][r] = e;
      p += e;
    }
    p += __shfl_xor(p, 16, 64);
    p += __shfl_xor(p, 32, 64);
    ps[sgr] = p;
  }
  if (lane < 16) {
#pragma unroll
    for (int sgr = 0; sgr < 4; ++sgr) red[wid][(sgr << 4) + sg] = ps[sgr];
  }
  __syncthreads();
  if (t < 64) gsums[t] = red[0][t] + red[1][t] + red[2][t] + red[3][t];
  __syncthreads();

  // ---- a, a' = a*invn, suma ----
  float sk[4] = {0.f, 0.f, 0.f, 0.f};
#pragma unroll
  for (int sgr = 0; sgr < 4; ++sgr) {
    float rinv = 1.0f / gsums[(sgr << 4) + col];
#pragma unroll
    for (int r = 0; r < 4; ++r) {
      float av = le[sgr][r] * rinv;            // a
      sk[r] += av;
      float apv = av * li[sgr];                // a' = a*invn[s]
      int k = (wid << 4) + (quad << 2) + r;
      ap[((size_t)((n << 6) + k) << 10) + s0 + (sgr << 4) + col] =
          (unsigned short)f2bf(apv);
    }
  }
#pragma unroll
  for (int r = 0; r < 4; ++r) {
    sk[r] += __shfl_xor(sk[r], 1, 64);
    sk[r] += __shfl_xor(sk[r], 2, 64);
    sk[r] += __shfl_xor(sk[r], 4, 64);
    sk[r] += __shfl_xor(sk[r], 8, 64);
  }
  if (col == 0) {
#pragma unroll
    for (int r = 0; r < 4; ++r)
      atomicAdd(&suma[(n << 6) + (wid << 4) + (quad << 2) + r], sk[r]);
  }
}

// K3: vlad^T[c,k] = sum_s x[c,s]*a'[k,s]  (bf16 MFMA, x as A, a' as B),
// then - suma[k]*cent[k,c], rnorm2 atomics, LDS-transposed coalesced store.
// x staged as bf16 (A-frag = single ds_read_b128, no per-step cvt);
// lt output buffer aliases the dead tiles (LDS 18 KB total).
__global__ __launch_bounds__(256) void k3_mfma(
    const float* __restrict__ x, const unsigned short* __restrict__ ap,
    const float* __restrict__ cent, const float* __restrict__ suma,
    float* __restrict__ out, float* __restrict__ rnorm2) {
  __shared__ __align__(16) char sm[64 * 72 * 2 * 2];  // 18432 B
  short (*xb)[72] = reinterpret_cast<short(*)[72]>(sm);          // [c][s] bf16
  short (*at)[72] = reinterpret_cast<short(*)[72]>(sm + 9216);   // [k][s] bf16
  float (*lt)[68] = reinterpret_cast<float(*)[68]>(sm);          // [k][c] (epilogue)

  const int n = blockIdx.y;
  const int c0 = blockIdx.x << 6;
  const int t = threadIdx.x;
  const int lane = t & 63;
  const int wid = t >> 6;        // c-band
  const int col = t & 15;
  const int quad = (t >> 4) & 3;
  const int cr = t >> 4;
  const int sg = t & 15;

  f32x4 acc[4] = {{0,0,0,0},{0,0,0,0},{0,0,0,0},{0,0,0,0}};

  for (int s0 = 0; s0 < 1024; s0 += 64) {
#pragma unroll
    for (int p = 0; p < 4; ++p) {
      int c = cr + (p << 4);
      float4 g = *(const float4*)&x[((size_t)((n << 9) + c0 + c) << 10) + s0 + (sg << 2)];
      short4v hx; hx.x = f2bf(g.x); hx.y = f2bf(g.y); hx.z = f2bf(g.z); hx.w = f2bf(g.w);
      *(short4v*)&xb[c][sg << 2] = hx;
      ushort4v a4 = *(const ushort4v*)&ap[((size_t)((n << 6) + c) << 10) + s0 + (sg << 2)];
      *(ushort4v*)&at[c][sg << 2] = a4;
    }
    __syncthreads();
#pragma unroll
    for (int ss = 0; ss < 64; ss += 32) {
      bf16x8 af = *(const bf16x8*)&xb[(wid << 4) + col][ss + (quad << 3)];
#pragma unroll
      for (int kt = 0; kt < 4; ++kt) {
        bf16x8 bfr = *(const bf16x8*)&at[(kt << 4) + col][ss + (quad << 3)];
        acc[kt] = __builtin_amdgcn_mfma_f32_16x16x32_bf16(af, bfr, acc[kt], 0, 0, 0);
      }
    }
    __syncthreads();
  }

  // epilogue: lane holds D[c = wid*16+quad*4+r][k = kt*16+col]
  float sa[4];
#pragma unroll
  for (int kt = 0; kt < 4; ++kt) sa[kt] = suma[(n << 6) + (kt << 4) + col];
  const int crow = (wid << 4) + (quad << 2);
  float r2[4] = {0.f, 0.f, 0.f, 0.f};
#pragma unroll
  for (int kt = 0; kt < 4; ++kt) {
    int k = (kt << 4) + col;
#pragma unroll
    for (int r = 0; r < 4; ++r) {
      int c = crow + r;
      float ce = cent[(k << 9) + c0 + c];
      float val = acc[kt][r] - sa[kt] * ce;
      r2[kt] = fmaf(val, val, r2[kt]);
      lt[k][c] = val;
    }
  }
#pragma unroll
  for (int kt = 0; kt < 4; ++kt) {
    r2[kt] += __shfl_xor(r2[kt], 16, 64);
    r2[kt] += __shfl_xor(r2[kt], 32, 64);
  }
  if (lane < 16) {
#pragma unroll
    for (int kt = 0; kt < 4; ++kt)
      atomicAdd(&rnorm2[(n << 6) + (kt << 4) + sg], r2[kt]);
  }
  __syncthreads();
  // coalesced store of the 64k x 64c tile
#pragma unroll
  for (int u = 0; u < 4; ++u) {
    int k = t >> 2;
    int c = ((t & 3) << 2) + (u << 4);
    float4 v = *(const float4*)&lt[k][c];
    *(float4*)&out[((size_t)((n << 6) + k) << 9) + c0 + c] = v;
  }
}

// K4: fac[n,k] = intra-norm factor * global-norm factor
__global__ __launch_bounds__(64) void k4_factors(const float* __restrict__ rnorm2,
                                                 float* __restrict__ fac) {
  int n = blockIdx.x, k = threadIdx.x;
  float r2 = rnorm2[(n << 6) + k];
  float rn = sqrtf(r2);
  float f = 1.0f / fmaxf(rn, EPSF);
  float nr = rn * f;
  float g = nr * nr;
#pragma unroll
  for (int off = 32; off > 0; off >>= 1) g += __shfl_xor(g, off, 64);
  fac[(n << 6) + k] = f * (1.0f / fmaxf(sqrtf(g), EPSF));
}

// K5: out *= fac  (in place; d_out fully rewritten by K3 each call)
__global__ __launch_bounds__(256) void k5_scale(const float* __restrict__ vlad,
                                                const float* __restrict__ fac,
                                                float* __restrict__ out) {
  int idx = blockIdx.x * 256 + threadIdx.x;  // float4 index
  float4 v = ((const float4*)vlad)[idx];
  float f = fac[idx >> 7];
  float4 o;
  o.x = v.x * f; o.y = v.y * f; o.z = v.z * f; o.w = v.w * f;
  ((float4*)out)[idx] = o;
}

extern "C" void kernel_launch(void* const* d_in, const int* in_sizes, int n_in,
                              void* d_out, int out_size, void* d_ws, size_t ws_size,
                              hipStream_t stream) {
  (void)in_sizes; (void)n_in; (void)out_size; (void)ws_size;
  const float* x = (const float*)d_in[0];     // (64,512,32,32)
  const float* w = (const float*)d_in[1];     // (64,512)
  const float* cent = (const float*)d_in[2];  // (64,512)
  float* out = (float*)d_out;                 // (64, 64*512)

  float* ws = (float*)d_ws;
  float* suma = ws;                                   // 4096
  float* rnorm2 = ws + 4096;                          // 4096
  float* fac = ws + 8192;                             // 4096
  unsigned short* ap = (unsigned short*)(ws + 12288); // 64*64*1024 bf16 = 8 MB

  hipMemsetAsync(ws, 0, 8192 * sizeof(float), stream);  // suma + rnorm2
  k2_mfma<<<dim3(16, 64), 256, 0, stream>>>(x, w, ap, suma);
  k3_mfma<<<dim3(8, 64), 256, 0, stream>>>(x, ap, cent, suma, out, rnorm2);
  k4_factors<<<64, 64, 0, stream>>>(rnorm2, fac);
  k5_scale<<<2048, 256, 0, stream>>>(out, fac, out);
}